// Round 4
// baseline (488.021 us; speedup 1.0000x reference)
//
#include <hip/hip_runtime.h>
#include <hip/hip_fp16.h>

// DynamicRouting: votes [B=32, NIN=2048, NOUT=64, ATOMS=16] fp32, 3 iters.
// R8: after two infra-level container failures on the novel 4-launch
// structure (R6/R7), revert to the EXACT harness-verified R0 structure
// (6 launches, 446us: ROWS_PER_WAVE=8, CHUNKS=64, single partials buffer,
// standalone squash_reduce) with ONE change: fp16 vote cache.
//  - pass 0 transcodes votes fp32->fp16 into ws (uint2 stores, 512 B
//    contiguous per instruction); passes 1-2 read 128 MiB instead of 256.
//  - ws_size guard: if the 136.5 MiB doesn't fit, run the literal R0 fp32
//    pass instead (8.125 MiB) -- no OOB possible either way.
// Error budget: fp16 vote err ~5e-4 -> logit err ~2e-3 -> pose err ~5e-3,
// vs threshold 2e-2 (R0 margin was 1e-3).
// fp16 fragment mapping (uint4 load j in {0,1} at row-idx j*64+lane):
// out oj = j*32 + (lane>>1), atoms [8p..8p+7], p = lane&1. Logit
// atom-reduce: ONE butterfly (mask 1); softmax denom: masks 2..32.

#define NB 32
#define NIN 2048
#define NOUT 64
#define ATOMS 16
#define EPSF 1e-9f

#define ROWS_PER_WAVE 8
#define WAVES_PER_BLOCK 4
#define ROWS_PER_BLOCK (ROWS_PER_WAVE * WAVES_PER_BLOCK) // 32
#define CHUNKS (NIN / ROWS_PER_BLOCK)                    // 64
#define RBATCH 2

__device__ __forceinline__ float4 f4add(float4 a, float4 b) {
    return make_float4(a.x + b.x, a.y + b.y, a.z + b.z, a.w + b.w);
}
__device__ __forceinline__ float4 f4fma(float c, float4 v, float4 a) {
    return make_float4(fmaf(c, v.x, a.x), fmaf(c, v.y, a.y),
                       fmaf(c, v.z, a.z), fmaf(c, v.w, a.w));
}
__device__ __forceinline__ float f4dot(float4 a, float4 b) {
    float d = a.x * b.x;
    d = fmaf(a.y, b.y, d); d = fmaf(a.z, b.z, d); d = fmaf(a.w, b.w, d);
    return d;
}

// ---------------- pass 0: uniform c = 1/64, optional fp16 transcode -------
template <int TRANSCODE>
__global__ __launch_bounds__(256, 4) void route0_transcode(
    const float4* __restrict__ votes4,
    uint2* __restrict__ votesh,
    float4* __restrict__ partials4)
{
    const int b     = blockIdx.x / CHUNKS;
    const int chunk = blockIdx.x % CHUNKS;
    const int wave  = threadIdx.x >> 6;
    const int lane  = threadIdx.x & 63;

    float4 acc[4];
#pragma unroll
    for (int j = 0; j < 4; ++j) acc[j] = make_float4(0.f, 0.f, 0.f, 0.f);

    const int in0 = chunk * ROWS_PER_BLOCK + wave * ROWS_PER_WAVE;
    const float4* vrow = votes4 + (size_t)(b * NIN + in0) * 256 + lane;
    uint2* hrow = votesh + (size_t)(b * NIN + in0) * 256 + lane;

    for (int r0 = 0; r0 < ROWS_PER_WAVE; r0 += RBATCH) {
        float4 v[RBATCH][4];
#pragma unroll
        for (int r = 0; r < RBATCH; ++r) {
            const float4* vp = vrow + (size_t)(r0 + r) * 256;
#pragma unroll
            for (int j = 0; j < 4; ++j) v[r][j] = vp[j * 64]; // 1 KB/instr
        }
#pragma unroll
        for (int r = 0; r < RBATCH; ++r) {
#pragma unroll
            for (int j = 0; j < 4; ++j) {
                acc[j] = f4add(acc[j], v[r][j]);
                if (TRANSCODE) {
                    __half2 h01 = __floats2half2_rn(v[r][j].x, v[r][j].y);
                    __half2 h23 = __floats2half2_rn(v[r][j].z, v[r][j].w);
                    uint2 pk;
                    pk.x = *(const unsigned int*)&h01;
                    pk.y = *(const unsigned int*)&h23;
                    (hrow + (size_t)(r0 + r) * 256)[j * 64] = pk; // 512 B/instr
                }
            }
        }
    }
#pragma unroll
    for (int j = 0; j < 4; ++j) {
        acc[j].x *= (1.f / 64.f); acc[j].y *= (1.f / 64.f);
        acc[j].z *= (1.f / 64.f); acc[j].w *= (1.f / 64.f);
    }

    __shared__ float4 red4[WAVES_PER_BLOCK * 256]; // 16 KiB
#pragma unroll
    for (int j = 0; j < 4; ++j)
        red4[wave * 256 + j * 64 + lane] = acc[j];
    __syncthreads();

    float4* pblock4 = partials4 + ((size_t)(b * CHUNKS + chunk) << 8);
    {
        int idx = threadIdx.x;
        float4 a = red4[idx], b2 = red4[256 + idx], c = red4[512 + idx], d = red4[768 + idx];
        float4 t;
        t.x = (a.x + b2.x) + (c.x + d.x);
        t.y = (a.y + b2.y) + (c.y + d.y);
        t.z = (a.z + b2.z) + (c.z + d.z);
        t.w = (a.w + b2.w) + (c.w + d.w);
        pblock4[idx] = t;
    }
}

// ---------------- passes 1-2, fp16 votes ----------------------------------
__global__ __launch_bounds__(256, 4) void route_pose_fp16(
    const uint4* __restrict__ voteshv,
    const float4* __restrict__ pose_accum4,
    float4* __restrict__ partials4)
{
    const int b     = blockIdx.x / CHUNKS;
    const int chunk = blockIdx.x % CHUNKS;
    const int wave  = threadIdx.x >> 6;
    const int lane  = threadIdx.x & 63;

    // lane's pose fragments: atoms [8p..8p+7] of out oj = j*32 + (lane>>1)
    float4 pseh[2][2];
#pragma unroll
    for (int j = 0; j < 2; ++j)
#pragma unroll
        for (int h = 0; h < 2; ++h)
            pseh[j][h] = pose_accum4[(size_t)b * 256
                                     + (j * 32 + (lane >> 1)) * 4 + (lane & 1) * 2 + h];

    float4 acc[2][2];
#pragma unroll
    for (int j = 0; j < 2; ++j)
#pragma unroll
        for (int h = 0; h < 2; ++h) acc[j][h] = make_float4(0.f, 0.f, 0.f, 0.f);

    const int in0 = chunk * ROWS_PER_BLOCK + wave * ROWS_PER_WAVE;
    const uint4* vrow = voteshv + (size_t)(b * NIN + in0) * 128 + lane;

    for (int r0 = 0; r0 < ROWS_PER_WAVE; r0 += RBATCH) {
        float4 va[RBATCH][2][2];
        float lg[RBATCH][2];
#pragma unroll
        for (int r = 0; r < RBATCH; ++r) {
#pragma unroll
            for (int j = 0; j < 2; ++j) {
                uint4 q = vrow[(size_t)(r0 + r) * 128 + j * 64]; // 1 KB/instr
                float2 f0 = __half22float2(*(const __half2*)&q.x);
                float2 f1 = __half22float2(*(const __half2*)&q.y);
                float2 f2 = __half22float2(*(const __half2*)&q.z);
                float2 f3 = __half22float2(*(const __half2*)&q.w);
                va[r][j][0] = make_float4(f0.x, f0.y, f1.x, f1.y);
                va[r][j][1] = make_float4(f2.x, f2.y, f3.x, f3.y);
                lg[r][j] = f4dot(va[r][j][0], pseh[j][0]) +
                           f4dot(va[r][j][1], pseh[j][1]);
            }
        }
        // partner lane (^1) holds the other 8 atoms of the same out
#pragma unroll
        for (int r = 0; r < RBATCH; ++r)
#pragma unroll
            for (int j = 0; j < 2; ++j)
                lg[r][j] += __shfl_xor(lg[r][j], 1, 64);

        float e[RBATCH][2], s[RBATCH];
#pragma unroll
        for (int r = 0; r < RBATCH; ++r) {
            e[r][0] = __expf(lg[r][0]);
            e[r][1] = __expf(lg[r][1]);
            s[r] = e[r][0] + e[r][1];
        }
        // denom over the 32 lane-pairs -> full softmax denom over 64 outs
#pragma unroll
        for (int mask = 2; mask <= 32; mask <<= 1)
#pragma unroll
            for (int r = 0; r < RBATCH; ++r)
                s[r] += __shfl_xor(s[r], mask, 64);

#pragma unroll
        for (int r = 0; r < RBATCH; ++r) {
            float inv = __frcp_rn(s[r]);
#pragma unroll
            for (int j = 0; j < 2; ++j) {
                float c = e[r][j] * inv;
                acc[j][0] = f4fma(c, va[r][j][0], acc[j][0]);
                acc[j][1] = f4fma(c, va[r][j][1], acc[j][1]);
            }
        }
    }

    __shared__ float4 red4[WAVES_PER_BLOCK * 256]; // 16 KiB
    // canonical float4 index = oj*4 + 2p + h = j*128 + (lane>>1)*4 + (lane&1)*2 + h
#pragma unroll
    for (int j = 0; j < 2; ++j)
#pragma unroll
        for (int h = 0; h < 2; ++h)
            red4[wave * 256 + j * 128 + (lane >> 1) * 4 + (lane & 1) * 2 + h] = acc[j][h];
    __syncthreads();

    float4* pblock4 = partials4 + ((size_t)(b * CHUNKS + chunk) << 8);
    {
        int idx = threadIdx.x;
        float4 a = red4[idx], b2 = red4[256 + idx], c = red4[512 + idx], d = red4[768 + idx];
        float4 t;
        t.x = (a.x + b2.x) + (c.x + d.x);
        t.y = (a.y + b2.y) + (c.y + d.y);
        t.z = (a.z + b2.z) + (c.z + d.z);
        t.w = (a.w + b2.w) + (c.w + d.w);
        pblock4[idx] = t;
    }
}

// ---------------- passes 1-2, fp32 fallback (exact R0 body) ---------------
__global__ __launch_bounds__(256, 4) void route_pose_fp32(
    const float4* __restrict__ votes4,
    const float4* __restrict__ pose_accum4,
    float4* __restrict__ partials4)
{
    const int b     = blockIdx.x / CHUNKS;
    const int chunk = blockIdx.x % CHUNKS;
    const int wave  = threadIdx.x >> 6;
    const int lane  = threadIdx.x & 63;

    float4 pse[4];
#pragma unroll
    for (int j = 0; j < 4; ++j)
        pse[j] = pose_accum4[(b * NOUT + j * 16 + (lane >> 2)) * 4 + (lane & 3)];

    float4 acc[4];
#pragma unroll
    for (int j = 0; j < 4; ++j) acc[j] = make_float4(0.f, 0.f, 0.f, 0.f);

    const int in0 = chunk * ROWS_PER_BLOCK + wave * ROWS_PER_WAVE;
    const float4* vrow = votes4 + (size_t)(b * NIN + in0) * 256 + lane;

    for (int r0 = 0; r0 < ROWS_PER_WAVE; r0 += RBATCH) {
        float4 v[RBATCH][4];
        float lg[RBATCH][4];
#pragma unroll
        for (int r = 0; r < RBATCH; ++r) {
            const float4* vp = vrow + (size_t)(r0 + r) * 256;
#pragma unroll
            for (int j = 0; j < 4; ++j) {
                v[r][j] = vp[j * 64];
                lg[r][j] = f4dot(v[r][j], pse[j]);
            }
        }
#pragma unroll
        for (int mask = 1; mask <= 2; mask <<= 1)
#pragma unroll
            for (int r = 0; r < RBATCH; ++r)
#pragma unroll
                for (int j = 0; j < 4; ++j)
                    lg[r][j] += __shfl_xor(lg[r][j], mask, 64);

        float e[RBATCH][4], s[RBATCH];
#pragma unroll
        for (int r = 0; r < RBATCH; ++r) {
            float t = 0.f;
#pragma unroll
            for (int j = 0; j < 4; ++j) { e[r][j] = __expf(lg[r][j]); t += e[r][j]; }
            s[r] = t;
        }
#pragma unroll
        for (int mask = 4; mask <= 32; mask <<= 1)
#pragma unroll
            for (int r = 0; r < RBATCH; ++r)
                s[r] += __shfl_xor(s[r], mask, 64);

#pragma unroll
        for (int r = 0; r < RBATCH; ++r) {
            float inv = __frcp_rn(s[r]);
#pragma unroll
            for (int j = 0; j < 4; ++j)
                acc[j] = f4fma(e[r][j] * inv, v[r][j], acc[j]);
        }
    }

    __shared__ float4 red4[WAVES_PER_BLOCK * 256];
#pragma unroll
    for (int j = 0; j < 4; ++j)
        red4[wave * 256 + j * 64 + lane] = acc[j];
    __syncthreads();

    float4* pblock4 = partials4 + ((size_t)(b * CHUNKS + chunk) << 8);
    {
        int idx = threadIdx.x;
        float4 a = red4[idx], b2 = red4[256 + idx], c = red4[512 + idx], d = red4[768 + idx];
        float4 t;
        t.x = (a.x + b2.x) + (c.x + d.x);
        t.y = (a.y + b2.y) + (c.y + d.y);
        t.z = (a.z + b2.z) + (c.z + d.z);
        t.w = (a.w + b2.w) + (c.w + d.w);
        pblock4[idx] = t;
    }
}

// ---- reduce 64 chunk-partials, squash (exact R0 kernel) ------------------
__global__ __launch_bounds__(256) void squash_reduce(
    const float* __restrict__ partials,
    float* __restrict__ pose_accum,
    float* __restrict__ d_out,
    int mode)
{
    int gid = blockIdx.x * 256 + threadIdx.x;  // < NB*NOUT*ATOMS = 32768
    int b  = gid >> 10;
    int oa = gid & 1023;
    const float* p = partials + ((size_t)b << 16) + oa;
    float s0 = 0.f, s1 = 0.f, s2 = 0.f, s3 = 0.f;
#pragma unroll
    for (int c = 0; c < CHUNKS; c += 4) {
        s0 += p[(c + 0) << 10];
        s1 += p[(c + 1) << 10];
        s2 += p[(c + 2) << 10];
        s3 += p[(c + 3) << 10];
    }
    float s = (s0 + s1) + (s2 + s3);

    float sq = s * s;
#pragma unroll
    for (int mask = 1; mask < ATOMS; mask <<= 1)
        sq += __shfl_xor(sq, mask, 64);
    float norm = sqrtf(sq + EPSF);
    float f = (sq / (1.0f + sq)) / norm;
    float pse = f * s;
    if (mode == 0) {
        pose_accum[gid] = pse;
    } else if (mode == 1) {
        pose_accum[gid] += pse;
    } else {
        d_out[gid] = pse;
        if ((gid & (ATOMS - 1)) == 0) {
            float psq = f * f * sq; // sum over atoms of pose^2
            d_out[NB * NOUT * ATOMS + (gid >> 4)] = sqrtf(psq + EPSF);
        }
    }
}

extern "C" void kernel_launch(void* const* d_in, const int* in_sizes, int n_in,
                              void* d_out, int out_size, void* d_ws, size_t ws_size,
                              hipStream_t stream) {
    const float4* votes4 = (const float4*)d_in[0];
    float* out = (float*)d_out;

    // ws: pose_accum 128 KiB | partials 8 MiB | votes_h 128 MiB (if it fits)
    float* pose_accum = (float*)d_ws;
    float* partials   = pose_accum + NB * NOUT * ATOMS;
    uint2* votesh     = (uint2*)(partials + NB * CHUNKS * 1024);
    const size_t need_fp16 =
        ((size_t)NB * NOUT * ATOMS + (size_t)NB * CHUNKS * 1024) * sizeof(float)
        + (size_t)NB * NIN * NOUT * ATOMS * sizeof(__half);

    dim3 blk(256);
    dim3 grid_route(NB * CHUNKS);            // 2048 blocks
    dim3 grid_sq(NB * NOUT * ATOMS / 256);   // 128 blocks

    const bool fp16_path = (ws_size >= need_fp16);

    if (fp16_path) {
        route0_transcode<1><<<grid_route, blk, 0, stream>>>(
            votes4, votesh, (float4*)partials);
    } else {
        route0_transcode<0><<<grid_route, blk, 0, stream>>>(
            votes4, nullptr, (float4*)partials);
    }
    squash_reduce<<<grid_sq, blk, 0, stream>>>(partials, pose_accum, nullptr, 0);

    if (fp16_path) {
        route_pose_fp16<<<grid_route, blk, 0, stream>>>(
            (const uint4*)votesh, (const float4*)pose_accum, (float4*)partials);
    } else {
        route_pose_fp32<<<grid_route, blk, 0, stream>>>(
            votes4, (const float4*)pose_accum, (float4*)partials);
    }
    squash_reduce<<<grid_sq, blk, 0, stream>>>(partials, pose_accum, nullptr, 1);

    if (fp16_path) {
        route_pose_fp16<<<grid_route, blk, 0, stream>>>(
            (const uint4*)votesh, (const float4*)pose_accum, (float4*)partials);
    } else {
        route_pose_fp32<<<grid_route, blk, 0, stream>>>(
            votes4, (const float4*)pose_accum, (float4*)partials);
    }
    squash_reduce<<<grid_sq, blk, 0, stream>>>(partials, nullptr, out, 2);
}